// Round 3
// baseline (253.455 us; speedup 1.0000x reference)
//
#include <hip/hip_runtime.h>
#include <cstdint>

typedef __attribute__((ext_vector_type(8))) __bf16 bf16x8;
typedef __attribute__((ext_vector_type(4))) float f32x4;
typedef __attribute__((ext_vector_type(8))) short short8;
typedef __attribute__((ext_vector_type(4))) float float4v;
typedef __attribute__((ext_vector_type(4))) unsigned uint4v;
typedef __attribute__((ext_vector_type(4))) unsigned short ushort4v;

__device__ __forceinline__ unsigned short f2bf(float f) {
    unsigned u = __builtin_bit_cast(unsigned, f);
    u += 0x7fffu + ((u >> 16) & 1u);   // RNE
    return (unsigned short)(u >> 16);
}
__device__ __forceinline__ float bf2f(unsigned short s) {
    return __builtin_bit_cast(float, (unsigned)s << 16);
}
__device__ __forceinline__ f32x4 mfma_bf16(bf16x8 a, bf16x8 b, f32x4 c) {
    return __builtin_amdgcn_mfma_f32_16x16x32_bf16(a, b, c, 0, 0, 0);
}
// pack 2 f32 -> 2 bf16 in one u32 (lo = first arg)
__device__ __forceinline__ unsigned pkbf(float lo, float hi) {
    unsigned r;
    asm("v_cvt_pk_bf16_f32 %0, %1, %2" : "=v"(r) : "v"(lo), "v"(hi));
    return r;
}

#define GLD16(g, l)                                                                     \
    __builtin_amdgcn_global_load_lds((const __attribute__((address_space(1))) void*)(g), \
                                     (__attribute__((address_space(3))) void*)(l), 16, 0, 0)

// ---------------------------------------------------------------------------
// fp32 -> bf16 conversion, 8 elems/thread.
// ---------------------------------------------------------------------------
__global__ void __launch_bounds__(256) cvt_f32_bf16(const float* __restrict__ src,
                                                    unsigned short* __restrict__ dst, int n8) {
    const int stride = gridDim.x * blockDim.x;
    for (int i = blockIdx.x * blockDim.x + threadIdx.x; i < n8; i += stride) {
        const float4v* s = (const float4v*)(src + (size_t)i * 8);
        float4v v0 = s[0], v1 = s[1];
        short8 o;
        o[0] = (short)f2bf(v0[0]); o[1] = (short)f2bf(v0[1]);
        o[2] = (short)f2bf(v0[2]); o[3] = (short)f2bf(v0[3]);
        o[4] = (short)f2bf(v1[0]); o[5] = (short)f2bf(v1[1]);
        o[6] = (short)f2bf(v1[2]); o[7] = (short)f2bf(v1[3]);
        *(short8*)(dst + (size_t)i * 8) = o;
    }
}

// ---------------------------------------------------------------------------
// C[M,N] = A[M,K]*B[N,K]^T + bias[N].  128x128 tile, BK=32, 4 waves, m97 structure.
// MODE 0: f32 C (ldc=N).   MODE 1 (QKV): n0<2048 -> bf16 qk buffer (ldc=2048);
//   n0>=2048 -> V part written TRANSPOSED into vT[bh][d=64][token=2048] bf16.
// ---------------------------------------------------------------------------
template <int MODE>
__global__ void __launch_bounds__(256) gemm_bt(const unsigned short* __restrict__ A,
                                               const unsigned short* __restrict__ B,
                                               const float* __restrict__ bias,
                                               void* __restrict__ C,
                                               unsigned short* __restrict__ vT,
                                               int M, int N, int K) {
    __shared__ __attribute__((aligned(16))) unsigned short As[128 * 32];
    __shared__ __attribute__((aligned(16))) unsigned short Bs[128 * 32];
    const int tid = threadIdx.x;
    const int w = tid >> 6, lane = tid & 63;
    const int a = lane & 15, g = lane >> 4;
    const int m0 = blockIdx.y * 128, n0 = blockIdx.x * 128;
    const int wr = (w >> 1) * 64, wc = (w & 1) * 64;

    f32x4 acc[4][4];
#pragma unroll
    for (int i = 0; i < 4; i++)
#pragma unroll
        for (int j = 0; j < 4; j++) acc[i][j] = (f32x4)(0.0f);

    const int r0 = tid >> 2;
    const int c0 = (tid & 3) * 8;
    const unsigned short* gA0 = A + (size_t)(m0 + r0) * K + c0;
    const unsigned short* gA1 = A + (size_t)(m0 + 64 + r0) * K + c0;
    const unsigned short* gB0 = B + (size_t)(n0 + r0) * K + c0;
    const unsigned short* gB1 = B + (size_t)(n0 + 64 + r0) * K + c0;
    char* ldsA = (char*)As + w * 1024;
    char* ldsB = (char*)Bs + w * 1024;

    for (int k0 = 0; k0 < K; k0 += 32) {
        GLD16(gA0 + k0, ldsA);
        GLD16(gA1 + k0, ldsA + 4096);
        GLD16(gB0 + k0, ldsB);
        GLD16(gB1 + k0, ldsB + 4096);
        __syncthreads();

        bf16x8 af[4], bfr[4];
#pragma unroll
        for (int i = 0; i < 4; i++) {
            af[i]  = *(const bf16x8*)&As[(wr + i * 16 + a) * 32 + g * 8];
            bfr[i] = *(const bf16x8*)&Bs[(wc + i * 16 + a) * 32 + g * 8];
        }
#pragma unroll
        for (int i = 0; i < 4; i++)
#pragma unroll
            for (int j = 0; j < 4; j++) acc[i][j] = mfma_bf16(af[i], bfr[j], acc[i][j]);
        __syncthreads();
    }

#pragma unroll
    for (int j = 0; j < 4; j++) {
        const int col = n0 + wc + j * 16 + a;
        const float bv = bias[col];
        if (MODE == 0) {
            float* Cf = (float*)C;
#pragma unroll
            for (int i = 0; i < 4; i++)
#pragma unroll
                for (int jr = 0; jr < 4; jr++) {
                    const int row = m0 + wr + i * 16 + g * 4 + jr;
                    Cf[(size_t)row * N + col] = acc[i][j][jr] + bv;
                }
        } else if (n0 < 2048) {  // Q/K part -> bf16, ldc = 2048
            unsigned short* Cb = (unsigned short*)C;
#pragma unroll
            for (int i = 0; i < 4; i++)
#pragma unroll
                for (int jr = 0; jr < 4; jr++) {
                    const int row = m0 + wr + i * 16 + g * 4 + jr;
                    Cb[(size_t)row * 2048 + col] = f2bf(acc[i][j][jr] + bv);
                }
        } else {  // V part -> vT[(b*16+h)][d][token], 4-token packs
            const int vd = col - 2048;
            const int hh = vd >> 6, dd = vd & 63;
#pragma unroll
            for (int i = 0; i < 4; i++) {
                const int token0 = m0 + wr + i * 16 + g * 4;
                const int bb = token0 >> 11, kl = token0 & 2047;
                ushort4v st;
#pragma unroll
                for (int jr = 0; jr < 4; jr++) st[jr] = f2bf(acc[i][j][jr] + bv);
                *(ushort4v*)(vT + ((size_t)((bb << 4) + hh) * 64 + dd) * 2048 + kl) = st;
            }
        }
    }
}

// ---------------------------------------------------------------------------
// Causal flash attention, swapped-QK^T in-register softmax, NO LDS/barriers.
// qk: [B*S, 2048] bf16 (Q cols 0..1023, K cols 1024..2047), vT: [32][64][2048].
// One wave = 16 q-rows; block = 4 independent waves (64 q-rows).
// Grid: 1024 flat; decode -> (bh, qt) with 4 heads pinned per XCD, heavy-first.
// S^T = mfma(A=K_sigma, B=Q): lane holds P[k(16 of 64)][q=lane&15]; sigma row
// permutation makes cvt_pk pairs land directly in PV's B-fragment layout.
// ---------------------------------------------------------------------------
__global__ void __launch_bounds__(256) attn_fwd(const unsigned short* __restrict__ qk,
                                                const unsigned short* __restrict__ vT,
                                                unsigned short* __restrict__ o) {
    constexpr int SL = 2048, DM = 1024, DH = 64, LDQ = 2048;
    const int flat = blockIdx.x;
    const int xcd = flat & 7, idx = flat >> 3;
    const int bh = xcd * 4 + (idx >> 5);   // 4 heads per XCD -> 2MB K+V in L2
    const int qt = 31 - (idx & 31);        // heavy q-tiles first
    const int b = bh >> 4, h = bh & 15;
    const int tid = threadIdx.x;
    const int w = tid >> 6, lane = tid & 63;
    const int n = lane & 15, g = lane >> 4;

    const int qbase = qt * 64 + w * 16;
    const int qs = qbase + n;  // this lane's q position (within sequence)

    // Q as B-operand (col n = q, k-dim = d), pre-scaled by 1/sqrt(64)
    bf16x8 qf[2];
    {
        const unsigned short* qp = qk + (size_t)(b * SL + qs) * LDQ + h * DH + g * 8;
        short8 qa = *(const short8*)qp;
        short8 qb = *(const short8*)(qp + 32);
        short8 sa, sb;
#pragma unroll
        for (int j = 0; j < 8; j++) {
            sa[j] = (short)f2bf(bf2f((unsigned short)qa[j]) * 0.125f);
            sb[j] = (short)f2bf(bf2f((unsigned short)qb[j]) * 0.125f);
        }
        qf[0] = __builtin_bit_cast(bf16x8, sa);
        qf[1] = __builtin_bit_cast(bf16x8, sb);
    }

    const unsigned short* kcolbase = qk + (size_t)(b * SL) * LDQ + 1024 + h * DH + g * 8;
    const unsigned short* vbase = vT + (size_t)bh * DH * SL;

    // sigma row offset for this lane's A-row (m = n)
    const int srow = 8 * (n >> 2) + (n & 3);

    f32x4 of[4];
#pragma unroll
    for (int i = 0; i < 4; i++) of[i] = (f32x4)(0.0f);
    float m_i = -1e30f, l_i = 0.0f;

    for (int t = 0; t <= qt; ++t) {
        const int k0 = t * 64;

        // ---- S^T = K_sigma * Q^T : p[nf][j] = P[k0+32(nf>>1)+8g+4(nf&1)+j][qs]
        f32x4 p[4];
#pragma unroll
        for (int nf = 0; nf < 4; nf++) {
            const int krow = k0 + srow + ((nf & 2) << 4) + ((nf & 1) << 2);
            const unsigned short* kp = kcolbase + (size_t)krow * LDQ;
            bf16x8 ka0 = *(const bf16x8*)kp;
            bf16x8 ka1 = *(const bf16x8*)(kp + 32);
            f32x4 acc = (f32x4)(0.0f);
            acc = mfma_bf16(ka0, qf[0], acc);
            acc = mfma_bf16(ka1, qf[1], acc);
            p[nf] = acc;
        }

        if (t == qt) {  // diagonal tile: causal mask
#pragma unroll
            for (int nf = 0; nf < 4; nf++) {
                const int kb = k0 + ((nf & 2) << 4) + ((nf & 1) << 2) + 8 * g;
#pragma unroll
                for (int j = 0; j < 4; j++)
                    if (kb + j > qs) p[nf][j] = -1e30f;
            }
        }

        // ---- in-lane max tree (16 values) + 2 cross-lane steps
        float a0 = fmaxf(fmaxf(p[0][0], p[0][1]), fmaxf(p[0][2], p[0][3]));
        float a1 = fmaxf(fmaxf(p[1][0], p[1][1]), fmaxf(p[1][2], p[1][3]));
        float a2 = fmaxf(fmaxf(p[2][0], p[2][1]), fmaxf(p[2][2], p[2][3]));
        float a3 = fmaxf(fmaxf(p[3][0], p[3][1]), fmaxf(p[3][2], p[3][3]));
        float mx = fmaxf(fmaxf(a0, a1), fmaxf(a2, a3));
        mx = fmaxf(mx, __shfl_xor(mx, 16));
        mx = fmaxf(mx, __shfl_xor(mx, 32));
        const float mnew = fmaxf(m_i, mx);

        // ---- exp + sum
#pragma unroll
        for (int nf = 0; nf < 4; nf++)
#pragma unroll
            for (int j = 0; j < 4; j++) p[nf][j] = __expf(p[nf][j] - mnew);
        float s0 = (p[0][0] + p[0][1]) + (p[0][2] + p[0][3]);
        float s1 = (p[1][0] + p[1][1]) + (p[1][2] + p[1][3]);
        float s2 = (p[2][0] + p[2][1]) + (p[2][2] + p[2][3]);
        float s3 = (p[3][0] + p[3][1]) + (p[3][2] + p[3][3]);
        float rs = (s0 + s1) + (s2 + s3);
        rs += __shfl_xor(rs, 16);
        rs += __shfl_xor(rs, 32);

        const float alpha = __expf(m_i - mnew);
        l_i = l_i * alpha + rs;
        m_i = mnew;
#pragma unroll
        for (int df = 0; df < 4; df++) of[df] *= alpha;

        // ---- P -> bf16 B-fragments (sigma makes this pure in-lane packing)
        uint4v u0, u1;
        u0[0] = pkbf(p[0][0], p[0][1]); u0[1] = pkbf(p[0][2], p[0][3]);
        u0[2] = pkbf(p[1][0], p[1][1]); u0[3] = pkbf(p[1][2], p[1][3]);
        u1[0] = pkbf(p[2][0], p[2][1]); u1[1] = pkbf(p[2][2], p[2][3]);
        u1[2] = pkbf(p[3][0], p[3][1]); u1[3] = pkbf(p[3][2], p[3][3]);
        const bf16x8 pf0 = __builtin_bit_cast(bf16x8, u0);
        const bf16x8 pf1 = __builtin_bit_cast(bf16x8, u1);

        // ---- O^T += V^T * P^T
#pragma unroll
        for (int df = 0; df < 4; df++) {
            const unsigned short* vp = vbase + (size_t)(df * 16 + n) * SL + k0 + g * 8;
            bf16x8 va0 = *(const bf16x8*)vp;
            bf16x8 va1 = *(const bf16x8*)(vp + 32);
            of[df] = mfma_bf16(va0, pf0, of[df]);
            of[df] = mfma_bf16(va1, pf1, of[df]);
        }
    }

    // ---- epilogue: lane holds O[d = df*16+4g+r][q = qs]
    const float inv = 1.0f / l_i;
    unsigned short* op = o + (size_t)(b * SL + qs) * DM + h * DH + 4 * g;
#pragma unroll
    for (int df = 0; df < 4; df++) {
        ushort4v st;
#pragma unroll
        for (int r = 0; r < 4; r++) st[r] = f2bf(of[df][r] * inv);
        *(ushort4v*)(op + df * 16) = st;
    }
}

// ---------------------------------------------------------------------------
extern "C" void kernel_launch(void* const* d_in, const int* in_sizes, int n_in,
                              void* d_out, int out_size, void* d_ws, size_t ws_size,
                              hipStream_t stream) {
    (void)in_sizes; (void)n_in; (void)out_size; (void)ws_size;
    const float* x    = (const float*)d_in[0];
    const float* Wqkv = (const float*)d_in[1];
    const float* bqkv = (const float*)d_in[2];
    const float* Wout = (const float*)d_in[3];
    const float* bout = (const float*)d_in[4];
    float* out = (float*)d_out;

    const int BS = 2, SL = 2048, DM = 1024;
    const int M = BS * SL;   // 4096
    const int N1 = 3 * DM;   // 3072
    const int K = DM;        // 1024

    // ws layout: x_bf 8M | wqkv_bf 6M | wout_bf 2M | qk 16M | vT 8M | attn_o 8M = 48M
    char* ws = (char*)d_ws;
    unsigned short* x_bf    = (unsigned short*)(ws);
    unsigned short* wqkv_bf = (unsigned short*)(ws + (8u << 20));
    unsigned short* wout_bf = (unsigned short*)(ws + (14u << 20));
    unsigned short* qkbuf   = (unsigned short*)(ws + (16u << 20));
    unsigned short* vTbuf   = (unsigned short*)(ws + (32u << 20));
    unsigned short* attn_o  = (unsigned short*)(ws + (40u << 20));

    cvt_f32_bf16<<<2048, 256, 0, stream>>>(x, x_bf, M * K / 8);
    cvt_f32_bf16<<<1536, 256, 0, stream>>>(Wqkv, wqkv_bf, N1 * K / 8);
    cvt_f32_bf16<<<512, 256, 0, stream>>>(Wout, wout_bf, DM * DM / 8);

    gemm_bt<1><<<dim3(N1 / 128, M / 128), 256, 0, stream>>>(x_bf, wqkv_bf, bqkv, qkbuf, vTbuf, M, N1, K);

    attn_fwd<<<dim3(1024), 256, 0, stream>>>(qkbuf, vTbuf, attn_o);

    gemm_bt<0><<<dim3(DM / 128, M / 128), 256, 0, stream>>>(attn_o, wout_bf, bout, out, nullptr, M, DM, K);
}

// Round 4
// 198.526 us; speedup vs baseline: 1.2767x; 1.2767x over previous
//
#include <hip/hip_runtime.h>
#include <cstdint>

typedef __attribute__((ext_vector_type(8))) __bf16 bf16x8;
typedef __attribute__((ext_vector_type(4))) float f32x4;
typedef __attribute__((ext_vector_type(8))) short short8;
typedef __attribute__((ext_vector_type(4))) float float4v;
typedef __attribute__((ext_vector_type(4))) unsigned uint4v;
typedef __attribute__((ext_vector_type(4))) unsigned short ushort4v;

__device__ __forceinline__ unsigned short f2bf(float f) {
    unsigned u = __builtin_bit_cast(unsigned, f);
    u += 0x7fffu + ((u >> 16) & 1u);   // RNE
    return (unsigned short)(u >> 16);
}
__device__ __forceinline__ float bf2f(unsigned short s) {
    return __builtin_bit_cast(float, (unsigned)s << 16);
}
__device__ __forceinline__ f32x4 mfma_bf16(bf16x8 a, bf16x8 b, f32x4 c) {
    return __builtin_amdgcn_mfma_f32_16x16x32_bf16(a, b, c, 0, 0, 0);
}
// pack 2 f32 -> 2 bf16 in one u32 (lo = first arg)
__device__ __forceinline__ unsigned pkbf(float lo, float hi) {
    unsigned r;
    asm("v_cvt_pk_bf16_f32 %0, %1, %2" : "=v"(r) : "v"(lo), "v"(hi));
    return r;
}

#define GLD16(g, l)                                                                     \
    __builtin_amdgcn_global_load_lds((const __attribute__((address_space(1))) void*)(g), \
                                     (__attribute__((address_space(3))) void*)(l), 16, 0, 0)

// ---------------------------------------------------------------------------
// fp32 -> bf16 conversion, 8 elems/thread.
// ---------------------------------------------------------------------------
__global__ void __launch_bounds__(256) cvt_f32_bf16(const float* __restrict__ src,
                                                    unsigned short* __restrict__ dst, int n8) {
    const int stride = gridDim.x * blockDim.x;
    for (int i = blockIdx.x * blockDim.x + threadIdx.x; i < n8; i += stride) {
        const float4v* s = (const float4v*)(src + (size_t)i * 8);
        float4v v0 = s[0], v1 = s[1];
        short8 o;
        o[0] = (short)f2bf(v0[0]); o[1] = (short)f2bf(v0[1]);
        o[2] = (short)f2bf(v0[2]); o[3] = (short)f2bf(v0[3]);
        o[4] = (short)f2bf(v1[0]); o[5] = (short)f2bf(v1[1]);
        o[6] = (short)f2bf(v1[2]); o[7] = (short)f2bf(v1[3]);
        *(short8*)(dst + (size_t)i * 8) = o;
    }
}

// ---------------------------------------------------------------------------
// C[M,N] = A[M,K]*B[N,K]^T + bias[N].  128x128 tile, BK=32, 4 waves, m97 structure.
// MODE 0: f32 C (ldc=N).   MODE 1 (QKV): n0<2048 -> bf16 qk buffer (ldc=2048);
//   n0>=2048 -> V part written TRANSPOSED into vT[bh][d=64][token=2048] bf16.
// ---------------------------------------------------------------------------
template <int MODE>
__global__ void __launch_bounds__(256) gemm_bt(const unsigned short* __restrict__ A,
                                               const unsigned short* __restrict__ B,
                                               const float* __restrict__ bias,
                                               void* __restrict__ C,
                                               unsigned short* __restrict__ vT,
                                               int M, int N, int K) {
    __shared__ __attribute__((aligned(16))) unsigned short As[128 * 32];
    __shared__ __attribute__((aligned(16))) unsigned short Bs[128 * 32];
    const int tid = threadIdx.x;
    const int w = tid >> 6, lane = tid & 63;
    const int a = lane & 15, g = lane >> 4;
    const int m0 = blockIdx.y * 128, n0 = blockIdx.x * 128;
    const int wr = (w >> 1) * 64, wc = (w & 1) * 64;

    f32x4 acc[4][4];
#pragma unroll
    for (int i = 0; i < 4; i++)
#pragma unroll
        for (int j = 0; j < 4; j++) acc[i][j] = (f32x4)(0.0f);

    const int r0 = tid >> 2;
    const int c0 = (tid & 3) * 8;
    const unsigned short* gA0 = A + (size_t)(m0 + r0) * K + c0;
    const unsigned short* gA1 = A + (size_t)(m0 + 64 + r0) * K + c0;
    const unsigned short* gB0 = B + (size_t)(n0 + r0) * K + c0;
    const unsigned short* gB1 = B + (size_t)(n0 + 64 + r0) * K + c0;
    char* ldsA = (char*)As + w * 1024;
    char* ldsB = (char*)Bs + w * 1024;

    for (int k0 = 0; k0 < K; k0 += 32) {
        GLD16(gA0 + k0, ldsA);
        GLD16(gA1 + k0, ldsA + 4096);
        GLD16(gB0 + k0, ldsB);
        GLD16(gB1 + k0, ldsB + 4096);
        __syncthreads();

        bf16x8 af[4], bfr[4];
#pragma unroll
        for (int i = 0; i < 4; i++) {
            af[i]  = *(const bf16x8*)&As[(wr + i * 16 + a) * 32 + g * 8];
            bfr[i] = *(const bf16x8*)&Bs[(wc + i * 16 + a) * 32 + g * 8];
        }
#pragma unroll
        for (int i = 0; i < 4; i++)
#pragma unroll
            for (int j = 0; j < 4; j++) acc[i][j] = mfma_bf16(af[i], bfr[j], acc[i][j]);
        __syncthreads();
    }

#pragma unroll
    for (int j = 0; j < 4; j++) {
        const int col = n0 + wc + j * 16 + a;
        const float bv = bias[col];
        if (MODE == 0) {
            float* Cf = (float*)C;
#pragma unroll
            for (int i = 0; i < 4; i++)
#pragma unroll
                for (int jr = 0; jr < 4; jr++) {
                    const int row = m0 + wr + i * 16 + g * 4 + jr;
                    Cf[(size_t)row * N + col] = acc[i][j][jr] + bv;
                }
        } else if (n0 < 2048) {  // Q/K part -> bf16, ldc = 2048
            unsigned short* Cb = (unsigned short*)C;
#pragma unroll
            for (int i = 0; i < 4; i++)
#pragma unroll
                for (int jr = 0; jr < 4; jr++) {
                    const int row = m0 + wr + i * 16 + g * 4 + jr;
                    Cb[(size_t)row * 2048 + col] = f2bf(acc[i][j][jr] + bv);
                }
        } else {  // V part -> vT[(b*16+h)][d][token], 4-token packs
            const int vd = col - 2048;
            const int hh = vd >> 6, dd = vd & 63;
#pragma unroll
            for (int i = 0; i < 4; i++) {
                const int token0 = m0 + wr + i * 16 + g * 4;
                const int bb = token0 >> 11, kl = token0 & 2047;
                ushort4v st;
#pragma unroll
                for (int jr = 0; jr < 4; jr++) st[jr] = f2bf(acc[i][j][jr] + bv);
                *(ushort4v*)(vT + ((size_t)((bb << 4) + hh) * 64 + dd) * 2048 + kl) = st;
            }
        }
    }
}

// ===========================================================================
// Causal flash attention v4: swapped QK^T, in-register softmax (exp2 domain),
// paired q-tiles (j, 31-j) per block -> uniform 33-tile cost, K/V register
// pipelining, per-lane l (cross-lane sum deferred to epilogue), defer-max.
// qk: [B*S, 2048] bf16 (Q | K), vT: [32][64][2048] bf16.
// Block = 4 independent waves; wave carries 16 lo-q rows + 16 hi-q rows.
// ===========================================================================

#define QKT(p, qf)                                                      \
    {                                                                   \
        _Pragma("unroll") for (int nf_ = 0; nf_ < 4; nf_++) {           \
            f32x4 acc_ = (f32x4)(0.0f);                                 \
            acc_ = mfma_bf16(ka[nf_], qf[0], acc_);                     \
            acc_ = mfma_bf16(kc[nf_], qf[1], acc_);                     \
            p[nf_] = acc_;                                              \
        }                                                               \
    }

#define DIAG_MASK(p, qs_, k0_)                                          \
    {                                                                   \
        _Pragma("unroll") for (int nf_ = 0; nf_ < 4; nf_++) {           \
            const int kb_ = (k0_) + ((nf_ & 2) << 4) + ((nf_ & 1) << 2) + 8 * g; \
            _Pragma("unroll") for (int e_ = 0; e_ < 4; e_++)            \
                if (kb_ + e_ > (qs_)) p[nf_][e_] = -1e30f;              \
        }                                                               \
    }

// p in log2 domain. Updates m_,l_,of_; produces packed bf16 B-fragments.
#define SOFTMAX_PACK(p, m_, l_, of_, pf0, pf1)                          \
    {                                                                   \
        float x0 = fmaxf(fmaxf(p[0][0], p[0][1]), fmaxf(p[0][2], p[0][3])); \
        float x1 = fmaxf(fmaxf(p[1][0], p[1][1]), fmaxf(p[1][2], p[1][3])); \
        float x2 = fmaxf(fmaxf(p[2][0], p[2][1]), fmaxf(p[2][2], p[2][3])); \
        float x3 = fmaxf(fmaxf(p[3][0], p[3][1]), fmaxf(p[3][2], p[3][3])); \
        float mx = fmaxf(fmaxf(x0, x1), fmaxf(x2, x3));                 \
        mx = fmaxf(mx, __shfl_xor(mx, 16));                             \
        mx = fmaxf(mx, __shfl_xor(mx, 32));                             \
        if (!__all(mx <= m_ + 8.0f)) {                                  \
            const float mn_ = fmaxf(m_, mx);                            \
            const float al_ = __builtin_amdgcn_exp2f(m_ - mn_);         \
            l_ *= al_;                                                  \
            _Pragma("unroll") for (int d_ = 0; d_ < 4; d_++) of_[d_] = of_[d_] * al_; \
            m_ = mn_;                                                   \
        }                                                               \
        float rs_ = 0.0f;                                               \
        _Pragma("unroll") for (int nf_ = 0; nf_ < 4; nf_++)             \
            _Pragma("unroll") for (int e_ = 0; e_ < 4; e_++) {          \
                p[nf_][e_] = __builtin_amdgcn_exp2f(p[nf_][e_] - m_);   \
                rs_ += p[nf_][e_];                                      \
            }                                                           \
        l_ += rs_;                                                      \
        uint4v u0_, u1_;                                                \
        u0_[0] = pkbf(p[0][0], p[0][1]); u0_[1] = pkbf(p[0][2], p[0][3]); \
        u0_[2] = pkbf(p[1][0], p[1][1]); u0_[3] = pkbf(p[1][2], p[1][3]); \
        u1_[0] = pkbf(p[2][0], p[2][1]); u1_[1] = pkbf(p[2][2], p[2][3]); \
        u1_[2] = pkbf(p[3][0], p[3][1]); u1_[3] = pkbf(p[3][2], p[3][3]); \
        pf0 = __builtin_bit_cast(bf16x8, u0_);                          \
        pf1 = __builtin_bit_cast(bf16x8, u1_);                          \
    }

#define PV(of_, pf0, pf1)                                               \
    {                                                                   \
        _Pragma("unroll") for (int df_ = 0; df_ < 4; df_++) {           \
            of_[df_] = mfma_bf16(va[df_], pf0, of_[df_]);               \
            of_[df_] = mfma_bf16(vc[df_], pf1, of_[df_]);               \
        }                                                               \
    }

#define LOAD_V()                                                        \
    {                                                                   \
        _Pragma("unroll") for (int df_ = 0; df_ < 4; df_++) {           \
            va[df_] = *(const bf16x8*)vp[df_];                          \
            vc[df_] = *(const bf16x8*)(vp[df_] + 32);                   \
            vp[df_] += 64;                                              \
        }                                                               \
    }

#define PREFETCH_K()                                                    \
    {                                                                   \
        _Pragma("unroll") for (int nf_ = 0; nf_ < 4; nf_++) {           \
            ka[nf_] = *(const bf16x8*)kp[nf_];                          \
            kc[nf_] = *(const bf16x8*)(kp[nf_] + 32);                   \
            kp[nf_] += 64 * 2048;                                       \
        }                                                               \
    }

#define WRITE_O(of_, l_, qs_)                                           \
    {                                                                   \
        float rl_ = l_;                                                 \
        rl_ += __shfl_xor(rl_, 16);                                     \
        rl_ += __shfl_xor(rl_, 32);                                     \
        const float inv_ = 1.0f / rl_;                                  \
        unsigned short* op_ = o + (size_t)(b * 2048 + (qs_)) * 1024 + h * 64 + 4 * g; \
        _Pragma("unroll") for (int df_ = 0; df_ < 4; df_++) {           \
            ushort4v st_;                                               \
            _Pragma("unroll") for (int r_ = 0; r_ < 4; r_++) st_[r_] = f2bf(of_[df_][r_] * inv_); \
            *(ushort4v*)(op_ + df_ * 16) = st_;                         \
        }                                                               \
    }

__global__ void __launch_bounds__(256) attn_fwd(const unsigned short* __restrict__ qk,
                                                const unsigned short* __restrict__ vT,
                                                unsigned short* __restrict__ o) {
    constexpr int SL = 2048, DH = 64, LDQ = 2048;
    constexpr float GAMMA = 0.18033688011112042f;  // 0.125 * log2(e)
    const int flat = blockIdx.x;                   // 512 blocks
    const int xcd = flat & 7, idx = flat >> 3;     // 64 per XCD
    const int bh = xcd * 4 + (idx >> 4);           // 4 heads pinned per XCD
    const int pj = idx & 15;                       // q-tile pair (pj, 31-pj)
    const int b = bh >> 4, h = bh & 15;
    const int tid = threadIdx.x;
    const int w = tid >> 6, lane = tid & 63;
    const int n = lane & 15, g = lane >> 4;

    const int qsL = pj * 64 + w * 16 + n;          // lo q row (this lane)
    const int qsH = (31 - pj) * 64 + w * 16 + n;   // hi q row
    const int tlast = 31 - pj;

    // Q fragments (B-operand), prescaled into log2 domain
    bf16x8 qL[2], qH[2];
    {
        const unsigned short* qpL = qk + (size_t)(b * SL + qsL) * LDQ + h * DH + g * 8;
        const unsigned short* qpH = qk + (size_t)(b * SL + qsH) * LDQ + h * DH + g * 8;
        short8 la = *(const short8*)qpL, lb = *(const short8*)(qpL + 32);
        short8 ha = *(const short8*)qpH, hb = *(const short8*)(qpH + 32);
        short8 s0, s1, s2, s3;
#pragma unroll
        for (int e = 0; e < 8; e++) {
            s0[e] = (short)f2bf(bf2f((unsigned short)la[e]) * GAMMA);
            s1[e] = (short)f2bf(bf2f((unsigned short)lb[e]) * GAMMA);
            s2[e] = (short)f2bf(bf2f((unsigned short)ha[e]) * GAMMA);
            s3[e] = (short)f2bf(bf2f((unsigned short)hb[e]) * GAMMA);
        }
        qL[0] = __builtin_bit_cast(bf16x8, s0);
        qL[1] = __builtin_bit_cast(bf16x8, s1);
        qH[0] = __builtin_bit_cast(bf16x8, s2);
        qH[1] = __builtin_bit_cast(bf16x8, s3);
    }

    // K pointers: sigma row permutation, one pointer per nf fragment
    const int srow = 8 * (n >> 2) + (n & 3);
    const unsigned short* kb0 = qk + (size_t)(b * SL) * LDQ + 1024 + h * DH + g * 8;
    const unsigned short* kp[4];
    kp[0] = kb0 + (size_t)(srow +  0) * LDQ;
    kp[1] = kb0 + (size_t)(srow +  4) * LDQ;
    kp[2] = kb0 + (size_t)(srow + 32) * LDQ;
    kp[3] = kb0 + (size_t)(srow + 36) * LDQ;
    // V pointers, one per df fragment
    const unsigned short* vbp = vT + (size_t)bh * DH * SL;
    const unsigned short* vp[4];
#pragma unroll
    for (int df = 0; df < 4; df++) vp[df] = vbp + (size_t)(df * 16 + n) * SL + g * 8;

    // current-tile K registers (prologue: tile 0)
    bf16x8 ka[4], kc[4];
    PREFETCH_K();

    f32x4 ofL[4], ofH[4];
#pragma unroll
    for (int i = 0; i < 4; i++) { ofL[i] = (f32x4)(0.0f); ofH[i] = (f32x4)(0.0f); }
    float mL = -1e30f, lL = 0.0f, mH = -1e30f, lH = 0.0f;

    // ---- phase 1: both q-groups, t = 0..pj (K/V regs shared) ----
    for (int t = 0; t <= pj; ++t) {
        f32x4 pL[4], pH[4];
        QKT(pL, qL);
        QKT(pH, qH);
        bf16x8 va[4], vc[4];
        LOAD_V();          // V(t): consumed after softmax
        PREFETCH_K();      // K(t+1): consumed next iteration (t<pj<=15<tlast)
        if (t == pj) DIAG_MASK(pL, qsL, t * 64);
        bf16x8 f0, f1, h0, h1;
        SOFTMAX_PACK(pL, mL, lL, ofL, f0, f1);
        SOFTMAX_PACK(pH, mH, lH, ofH, h0, h1);
        PV(ofL, f0, f1);
        PV(ofH, h0, h1);
    }
    WRITE_O(ofL, lL, qsL);  // lo group done; frees its registers

    // ---- phase 2: hi group only, t = pj+1..31-pj ----
    for (int t = pj + 1; t <= tlast; ++t) {
        f32x4 pH[4];
        QKT(pH, qH);
        bf16x8 va[4], vc[4];
        LOAD_V();
        if (t < tlast) PREFETCH_K();
        if (t == tlast) DIAG_MASK(pH, qsH, t * 64);
        bf16x8 h0, h1;
        SOFTMAX_PACK(pH, mH, lH, ofH, h0, h1);
        PV(ofH, h0, h1);
    }
    WRITE_O(ofH, lH, qsH);
}

// ---------------------------------------------------------------------------
extern "C" void kernel_launch(void* const* d_in, const int* in_sizes, int n_in,
                              void* d_out, int out_size, void* d_ws, size_t ws_size,
                              hipStream_t stream) {
    (void)in_sizes; (void)n_in; (void)out_size; (void)ws_size;
    const float* x    = (const float*)d_in[0];
    const float* Wqkv = (const float*)d_in[1];
    const float* bqkv = (const float*)d_in[2];
    const float* Wout = (const float*)d_in[3];
    const float* bout = (const float*)d_in[4];
    float* out = (float*)d_out;

    const int BS = 2, SL = 2048, DM = 1024;
    const int M = BS * SL;   // 4096
    const int N1 = 3 * DM;   // 3072
    const int K = DM;        // 1024

    // ws layout: x_bf 8M | wqkv_bf 6M | wout_bf 2M | qk 16M | vT 8M | attn_o 8M = 48M
    char* ws = (char*)d_ws;
    unsigned short* x_bf    = (unsigned short*)(ws);
    unsigned short* wqkv_bf = (unsigned short*)(ws + (8u << 20));
    unsigned short* wout_bf = (unsigned short*)(ws + (14u << 20));
    unsigned short* qkbuf   = (unsigned short*)(ws + (16u << 20));
    unsigned short* vTbuf   = (unsigned short*)(ws + (32u << 20));
    unsigned short* attn_o  = (unsigned short*)(ws + (40u << 20));

    cvt_f32_bf16<<<2048, 256, 0, stream>>>(x, x_bf, M * K / 8);
    cvt_f32_bf16<<<1536, 256, 0, stream>>>(Wqkv, wqkv_bf, N1 * K / 8);
    cvt_f32_bf16<<<512, 256, 0, stream>>>(Wout, wout_bf, DM * DM / 8);

    gemm_bt<1><<<dim3(N1 / 128, M / 128), 256, 0, stream>>>(x_bf, wqkv_bf, bqkv, qkbuf, vTbuf, M, N1, K);

    attn_fwd<<<dim3(512), 256, 0, stream>>>(qkbuf, vTbuf, attn_o);

    gemm_bt<0><<<dim3(DM / 128, M / 128), 256, 0, stream>>>(attn_o, wout_bf, bout, out, nullptr, M, DM, K);
}